// Round 1
// baseline (2710.741 us; speedup 1.0000x reference)
//
#include <hip/hip_runtime.h>
#include <math.h>

// Problem constants (reference: B=32, L=2048)
#define LLEN 2048
#define BATCH 32
#define N_PTS (LLEN - 2)     // 2046 embedded points
#define N_DEATH (LLEN - 3)   // 2045 MST edges / deaths
#define SORT_N 2048          // padded sort size
#define TPB 512              // threads per block (8 waves)
#define PT 4                 // elements per thread: 2048/512
#define NWAVE (TPB / 64)
#define BIG 1e30f

// One block per series. Dense Prim MST with register-resident points+mind,
// LDS only for point-broadcast + cross-wave argmin + final bitonic sort.
__global__ __launch_bounds__(TPB)
void topo_kernel(const float* __restrict__ pred,
                 const float* __restrict__ tgt,
                 float* __restrict__ topo /* [64][N_DEATH] */) {
    __shared__ float4 pp[SORT_N];        // embedded points (broadcast source)
    __shared__ float deaths[SORT_N];
    __shared__ float redV[2][NWAVE];     // double-buffered cross-wave argmin
    __shared__ int   redI[2][NWAVE];

    const int b = blockIdx.x;
    const float* x = (b < BATCH) ? (pred + b * LLEN) : (tgt + (b - BATCH) * LLEN);
    const int t = threadIdx.x;
    const int lane = t & 63;
    const int wid = t >> 6;

    // Register-resident points and min-distance array.
    // visited is encoded as m < 0 (squared distances are >= 0).
    float px[PT], py[PT], pz[PT], m[PT];
#pragma unroll
    for (int s = 0; s < PT; ++s) {
        int idx = t * PT + s;
        float a0 = 0.f, a1 = 0.f, a2 = 0.f;
        if (idx < N_PTS) { a0 = x[idx]; a1 = x[idx + 1]; a2 = x[idx + 2]; }
        px[s] = a0; py[s] = a1; pz[s] = a2;
        pp[idx] = make_float4(a0, a1, a2, 0.f);
        m[s] = (idx < N_PTS) ? BIG : -1.0f;   // pad slots permanently visited
    }
    __syncthreads();

    int j = 0;  // most recently added vertex (start: vertex 0)
    for (int i = 0; i < N_DEATH; ++i) {
        float4 pj = pp[j];  // broadcast LDS read, conflict-free
        float lv = BIG; int li = 0x7fffffff;
        // fused: update mind with distances to j, mark j visited, local argmin
#pragma unroll
        for (int s = 0; s < PT; ++s) {
            int idx = t * PT + s;
            float dx = px[s] - pj.x, dy = py[s] - pj.y, dz = pz[s] - pj.z;
            float d2 = dx * dx + dy * dy + dz * dz;
            float mm = m[s];
            float nm = fminf(mm, d2);
            nm = (mm < 0.f) ? mm : nm;        // visited stays visited
            nm = (idx == j) ? -1.f : nm;      // newly added -> visited
            m[s] = nm;
            bool better = (nm >= 0.f) && ((nm < lv) || (nm == lv && idx < li));
            lv = better ? nm : lv;
            li = better ? idx : li;
        }
        // wave-level butterfly argmin (tie-break: smallest index, like jnp.argmin)
#pragma unroll
        for (int off = 32; off >= 1; off >>= 1) {
            float ov = __shfl_xor(lv, off);
            int   oi = __shfl_xor(li, off);
            bool better = (ov < lv) || (ov == lv && oi < li);
            lv = better ? ov : lv;
            li = better ? oi : li;
        }
        const int buf = i & 1;
        if (lane == 0) { redV[buf][wid] = lv; redI[buf][wid] = li; }
        __syncthreads();   // single barrier per iteration (double-buffered slots)
        float jv = redV[buf][0]; int jn = redI[buf][0];
#pragma unroll
        for (int w = 1; w < NWAVE; ++w) {
            float ov = redV[buf][w]; int oi = redI[buf][w];
            bool better = (ov < jv) || (ov == jv && oi < jn);
            jv = better ? ov : jv;
            jn = better ? oi : jn;
        }
        j = jn;
        if (t == 0) deaths[i] = sqrtf(jv);   // sqrt only at record time
    }

    // pad then bitonic sort DESCENDING over SORT_N elements
    if (t < SORT_N - N_DEATH) deaths[N_DEATH + t] = -BIG;
    __syncthreads();

    for (int k = 2; k <= SORT_N; k <<= 1) {
        for (int jj = k >> 1; jj > 0; jj >>= 1) {
#pragma unroll
            for (int s = 0; s < SORT_N / TPB; ++s) {
                int ii = t + s * TPB;
                int ixj = ii ^ jj;
                if (ixj > ii) {
                    float a = deaths[ii], c = deaths[ixj];
                    bool descBlock = ((ii & k) == 0);
                    bool doSwap = descBlock ? (a < c) : (a > c);
                    if (doSwap) { deaths[ii] = c; deaths[ixj] = a; }
                }
            }
            __syncthreads();
        }
    }

    for (int e = t; e < N_DEATH; e += TPB)
        topo[b * N_DEATH + e] = deaths[e];
}

// Single-block deterministic reduction: MSE + 0.1 * topo MSE.
#define RTPB 1024
__global__ __launch_bounds__(RTPB)
void loss_kernel(const float* __restrict__ pred,
                 const float* __restrict__ tgt,
                 const float* __restrict__ topo,
                 float* __restrict__ out) {
    const int t = threadIdx.x;
    float msum = 0.f;
    const float4* p4 = (const float4*)pred;
    const float4* t4 = (const float4*)tgt;
    const int n4 = (BATCH * LLEN) / 4;   // 16384
    for (int e = t; e < n4; e += RTPB) {
        float4 a = p4[e], c = t4[e];
        float dx = a.x - c.x, dy = a.y - c.y, dz = a.z - c.z, dw = a.w - c.w;
        msum += dx * dx + dy * dy + dz * dz + dw * dw;
    }
    float tsum = 0.f;
    const int nt = BATCH * N_DEATH;      // 65440
    for (int e = t; e < nt; e += RTPB) {
        float d = topo[e] - topo[e + nt];
        tsum += d * d;
    }
    // block reduce
    __shared__ float sm[2][RTPB / 64];
#pragma unroll
    for (int off = 32; off >= 1; off >>= 1) {
        msum += __shfl_xor(msum, off);
        tsum += __shfl_xor(tsum, off);
    }
    int lane = t & 63, wid = t >> 6;
    if (lane == 0) { sm[0][wid] = msum; sm[1][wid] = tsum; }
    __syncthreads();
    if (t == 0) {
        float M = 0.f, T = 0.f;
#pragma unroll
        for (int w = 0; w < RTPB / 64; ++w) { M += sm[0][w]; T += sm[1][w]; }
        out[0] = M / (float)(BATCH * LLEN) + 0.1f * (T / (float)nt);
    }
}

extern "C" void kernel_launch(void* const* d_in, const int* in_sizes, int n_in,
                              void* d_out, int out_size, void* d_ws, size_t ws_size,
                              hipStream_t stream) {
    const float* pred = (const float*)d_in[0];
    const float* tgt  = (const float*)d_in[1];
    float* topo = (float*)d_ws;   // 64 * 2045 * 4 B = 523,520 B of scratch

    topo_kernel<<<2 * BATCH, TPB, 0, stream>>>(pred, tgt, topo);
    loss_kernel<<<1, RTPB, 0, stream>>>(pred, tgt, topo, (float*)d_out);
}

// Round 2
// 1203.105 us; speedup vs baseline: 2.2531x; 2.2531x over previous
//
#include <hip/hip_runtime.h>
#include <math.h>

// Problem constants (reference: B=32, L=2048)
#define LLEN 2048
#define BATCH 32
#define N_PTS (LLEN - 2)     // 2046 embedded points
#define N_DEATH (LLEN - 3)   // 2045 MST edges / deaths
#define SORT_N 2048          // padded sort size
#define TPB 256              // 4 waves: fewer barrier participants than 512
#define PT (SORT_N / TPB)    // 8 elements per thread
#define NW (TPB / 64)        // 4 waves
#define BIG 1e30f

// Wave64 unsigned-min reduction via DPP (VALU pipe, ~5cyc/step) instead of
// ds_swizzle (~100cyc/step). Result valid in lane 63.
// row_shr:1/2/4/8 accumulate within 16-lane rows; row_bcast:15/31 merge rows.
__device__ __forceinline__ unsigned dpp_umin6(unsigned v) {
    unsigned t;
    t = (unsigned)__builtin_amdgcn_update_dpp(-1, (int)v, 0x111, 0xF, 0xF, false);
    v = (t < v) ? t : v;
    t = (unsigned)__builtin_amdgcn_update_dpp(-1, (int)v, 0x112, 0xF, 0xF, false);
    v = (t < v) ? t : v;
    t = (unsigned)__builtin_amdgcn_update_dpp(-1, (int)v, 0x114, 0xF, 0xF, false);
    v = (t < v) ? t : v;
    t = (unsigned)__builtin_amdgcn_update_dpp(-1, (int)v, 0x118, 0xF, 0xF, false);
    v = (t < v) ? t : v;
    t = (unsigned)__builtin_amdgcn_update_dpp(-1, (int)v, 0x142, 0xF, 0xF, false);
    v = (t < v) ? t : v;
    t = (unsigned)__builtin_amdgcn_update_dpp(-1, (int)v, 0x143, 0xF, 0xF, false);
    v = (t < v) ? t : v;
    return v;
}

// One block per series. Register-resident Prim; LDS touched once per iteration
// (4-slot exchange, double-buffered -> single barrier per iteration).
// Visited encoding: m = -1.0f (0xBF800000 as uint > any positive float bits,
// so visited/pad entries lose every unsigned-compare argmin automatically,
// and fminf(-1, d2>=0) = -1 keeps them visited with no extra mask).
// Tie-breaking is arbitrary (first lane): all MSTs have the same edge-weight
// multiset and only the sorted weights are consumed.
__global__ __launch_bounds__(TPB)
void topo_kernel(const float* __restrict__ pred,
                 const float* __restrict__ tgt,
                 float* __restrict__ topo /* [64][N_DEATH] */) {
    __shared__ float deaths[SORT_N];
    __shared__ float4 xq[2][NW];   // (d2_bits, idx_bits, x, y) per wave
    __shared__ float  xz[2][NW];   // z per wave

    const int b = blockIdx.x;
    const float* x = (b < BATCH) ? (pred + b * LLEN) : (tgt + (b - BATCH) * LLEN);
    const int t = threadIdx.x;
    const int lane = t & 63;
    const int wid = t >> 6;

    float px[PT], py[PT], pz[PT], m[PT];
    int idxs[PT];
#pragma unroll
    for (int s = 0; s < PT; ++s) {
        int idx = t * PT + s;
        idxs[s] = idx;
        bool valid = idx < N_PTS;
        px[s] = valid ? x[idx]     : 0.f;
        py[s] = valid ? x[idx + 1] : 0.f;
        pz[s] = valid ? x[idx + 2] : 0.f;
        m[s]  = valid ? BIG : -1.0f;   // pads permanently "visited"
    }

    // start vertex 0
    float pjx = x[0], pjy = x[1], pjz = x[2];
    int j = 0;

    for (int i = 0; i < N_DEATH; ++i) {
        unsigned lv = 0xFFFFFFFFu;
        int li = 0;
        float cx = 0.f, cy = 0.f, cz = 0.f;
        // fused: distance-to-j update, mark j visited, local argmin w/ coords
#pragma unroll
        for (int s = 0; s < PT; ++s) {
            float dx = px[s] - pjx, dy = py[s] - pjy, dz = pz[s] - pjz;
            float d2 = dx * dx + dy * dy + dz * dz;
            float nm = fminf(m[s], d2);          // visited (-1) absorbs
            nm = (idxs[s] == j) ? -1.0f : nm;    // newly added -> visited
            m[s] = nm;
            unsigned nu = __float_as_uint(nm);   // uint order == float order (>=0)
            bool better = nu < lv;
            lv = better ? nu : lv;
            li = better ? idxs[s] : li;
            cx = better ? px[s] : cx;
            cy = better ? py[s] : cy;
            cz = better ? pz[s] : cz;
        }
        // wave min (VALU-pipe DPP), then winner lane writes its candidate
        unsigned wmin = dpp_umin6(lv);
        unsigned jv = (unsigned)__builtin_amdgcn_readlane((int)wmin, 63);
        unsigned long long mask = __ballot(lv == jv);
        int wl = __ffsll((unsigned long long)mask) - 1;   // first matching lane
        const int buf = i & 1;
        if (lane == wl) {
            xq[buf][wid] = make_float4(__uint_as_float(lv), __int_as_float(li), cx, cy);
            xz[buf][wid] = cz;
        }
        __syncthreads();   // single barrier per iteration (double-buffered)
        // cross-wave tournament (uniform, broadcast LDS reads)
        float4 q = xq[buf][0];
        float  qz = xz[buf][0];
#pragma unroll
        for (int w = 1; w < NW; ++w) {
            float4 qw = xq[buf][w];
            float  zw = xz[buf][w];
            bool better = __float_as_uint(qw.x) < __float_as_uint(q.x);
            q.x = better ? qw.x : q.x;
            q.y = better ? qw.y : q.y;
            q.z = better ? qw.z : q.z;
            q.w = better ? qw.w : q.w;
            qz  = better ? zw   : qz;
        }
        j = __float_as_int(q.y);
        pjx = q.z; pjy = q.w; pjz = qz;
        if (t == 0) deaths[i] = sqrtf(q.x);   // off the dependence chain
    }

    // pad then bitonic sort DESCENDING over SORT_N elements
    if (t < SORT_N - N_DEATH) deaths[N_DEATH + t] = -BIG;
    __syncthreads();

    for (int k = 2; k <= SORT_N; k <<= 1) {
        for (int jj = k >> 1; jj > 0; jj >>= 1) {
#pragma unroll
            for (int s = 0; s < SORT_N / TPB; ++s) {
                int ii = t + s * TPB;
                int ixj = ii ^ jj;
                if (ixj > ii) {
                    float a = deaths[ii], c = deaths[ixj];
                    bool descBlock = ((ii & k) == 0);
                    bool doSwap = descBlock ? (a < c) : (a > c);
                    if (doSwap) { deaths[ii] = c; deaths[ixj] = a; }
                }
            }
            __syncthreads();
        }
    }

    for (int e = t; e < N_DEATH; e += TPB)
        topo[b * N_DEATH + e] = deaths[e];
}

// Single-block deterministic reduction: MSE + 0.1 * topo MSE.
#define RTPB 1024
__global__ __launch_bounds__(RTPB)
void loss_kernel(const float* __restrict__ pred,
                 const float* __restrict__ tgt,
                 const float* __restrict__ topo,
                 float* __restrict__ out) {
    const int t = threadIdx.x;
    float msum = 0.f;
    const float4* p4 = (const float4*)pred;
    const float4* t4 = (const float4*)tgt;
    const int n4 = (BATCH * LLEN) / 4;   // 16384
    for (int e = t; e < n4; e += RTPB) {
        float4 a = p4[e], c = t4[e];
        float dx = a.x - c.x, dy = a.y - c.y, dz = a.z - c.z, dw = a.w - c.w;
        msum += dx * dx + dy * dy + dz * dz + dw * dw;
    }
    float tsum = 0.f;
    const int nt = BATCH * N_DEATH;      // 65440
    for (int e = t; e < nt; e += RTPB) {
        float d = topo[e] - topo[e + nt];
        tsum += d * d;
    }
    __shared__ float sm[2][RTPB / 64];
#pragma unroll
    for (int off = 32; off >= 1; off >>= 1) {
        msum += __shfl_xor(msum, off);
        tsum += __shfl_xor(tsum, off);
    }
    int lane = t & 63, wid = t >> 6;
    if (lane == 0) { sm[0][wid] = msum; sm[1][wid] = tsum; }
    __syncthreads();
    if (t == 0) {
        float M = 0.f, T = 0.f;
#pragma unroll
        for (int w = 0; w < RTPB / 64; ++w) { M += sm[0][w]; T += sm[1][w]; }
        out[0] = M / (float)(BATCH * LLEN) + 0.1f * (T / (float)nt);
    }
}

extern "C" void kernel_launch(void* const* d_in, const int* in_sizes, int n_in,
                              void* d_out, int out_size, void* d_ws, size_t ws_size,
                              hipStream_t stream) {
    const float* pred = (const float*)d_in[0];
    const float* tgt  = (const float*)d_in[1];
    float* topo = (float*)d_ws;   // 64 * 2045 * 4 B of scratch

    topo_kernel<<<2 * BATCH, TPB, 0, stream>>>(pred, tgt, topo);
    loss_kernel<<<1, RTPB, 0, stream>>>(pred, tgt, topo, (float*)d_out);
}

// Round 4
// 1130.693 us; speedup vs baseline: 2.3974x; 1.0640x over previous
//
#include <hip/hip_runtime.h>
#include <math.h>

// Problem constants (reference: B=32, L=2048)
#define LLEN 2048
#define BATCH 32
#define N_PTS (LLEN - 2)     // 2046 embedded points
#define N_DEATH (LLEN - 3)   // 2045 MST edges / deaths
#define SORT_N 2048
#define TPB 256              // 4 waves, one per SIMD
#define PT 8                 // elements per thread
#define NW 4                 // waves per block
#define BIG 1e30f

// Wave64 unsigned-min via DPP (VALU pipe). Result valid in lane 63.
__device__ __forceinline__ unsigned dpp_umin6(unsigned v) {
    unsigned t;
    t = (unsigned)__builtin_amdgcn_update_dpp(-1, (int)v, 0x111, 0xF, 0xF, false); // row_shr:1
    v = t < v ? t : v;
    t = (unsigned)__builtin_amdgcn_update_dpp(-1, (int)v, 0x112, 0xF, 0xF, false); // row_shr:2
    v = t < v ? t : v;
    t = (unsigned)__builtin_amdgcn_update_dpp(-1, (int)v, 0x114, 0xF, 0xF, false); // row_shr:4
    v = t < v ? t : v;
    t = (unsigned)__builtin_amdgcn_update_dpp(-1, (int)v, 0x118, 0xF, 0xF, false); // row_shr:8
    v = t < v ? t : v;
    t = (unsigned)__builtin_amdgcn_update_dpp(-1, (int)v, 0x142, 0xF, 0xF, false); // row_bcast:15
    v = t < v ? t : v;
    t = (unsigned)__builtin_amdgcn_update_dpp(-1, (int)v, 0x143, 0xF, 0xF, false); // row_bcast:31
    v = t < v ? t : v;
    return v;
}

// One block per series. Prim with packed (d2|idx) u32 candidates so every
// reduction step is v_min_u32. Cross-wave exchange is a LOCK-FREE polled LDS
// mailbox (no __syncthreads in the 2045-iteration loop):
//   value layout: [31:12] d2 (top 20 bits of fp32), [11] iteration-parity tag,
//                 [10:0] vertex index (0..2045).
//   Double buffer (i&1) separates i from i-1; tag parity ((i>>1)&1) separates
//   i from i-2; the reader's own progress rules out i-4 (to reach iteration i
//   it consumed every wave's i-1 publish). DS ops complete in-order per wave,
//   so one u32 carrying value+tag is race-free.
// DEADLOCK FIX (round 3 hang): an all-visited wave's lv stays 0xFFFFFFFF,
// whose bit 11 would corrupt the tag. Publish (smin & ~0x800) | tag — the
// sentinel keeps losing every cross-wave min, and at least one wave always
// holds an unvisited vertex, so the global winner is always legitimate.
// d2 truncation rel-err ~2.4e-4; sorted MST weights are 1-Lipschitz under
// metric perturbation -> loss error ~1e-3 << 4e-2 threshold.
// Visited = per-thread 8-bit mask. Winner coords via one broadcast
// ds_read_b128 of pp[j].
__global__ __launch_bounds__(TPB)
void topo_kernel(const float* __restrict__ pred,
                 const float* __restrict__ tgt,
                 float* __restrict__ topo /* [64][N_DEATH] */) {
    __shared__ float4 pp[SORT_N];
    __shared__ float deaths[SORT_N];
    __shared__ unsigned xslot[2 * NW];   // polled mailbox [buf][wave]

    const int b = blockIdx.x;
    const float* x = (b < BATCH) ? (pred + b * LLEN) : (tgt + (b - BATCH) * LLEN);
    const int t = threadIdx.x;
    const int lane = t & 63;
    const int wid = t >> 6;

    // mailbox init: tag bit = 1 mismatches iteration 0/1's expected tag 0
    if (t < 2 * NW) xslot[t] = 0x800u;

    float px[PT], py[PT], pz[PT];
    unsigned m[PT];      // packed running min-distance (d2_hi20 | 0 | idx)
    unsigned idxs[PT];
    unsigned vis = 0;    // bit s: vertex t*PT+s is visited (or padding)
#pragma unroll
    for (int s = 0; s < PT; ++s) {
        int idx = t * PT + s;
        idxs[s] = (unsigned)idx;
        bool valid = idx < N_PTS;
        px[s] = valid ? x[idx]     : 0.f;
        py[s] = valid ? x[idx + 1] : 0.f;
        pz[s] = valid ? x[idx + 2] : 0.f;
        pp[idx] = make_float4(px[s], py[s], pz[s], 0.f);
        m[s] = 0x7F800000u | idxs[s];           // +inf packed
        if (!valid || idx == 0) vis |= 1u << s; // pads + start vertex visited
    }
    __syncthreads();   // pp[] + mailbox init visible (only barrier before sort)

    int j = 0;
    float pjx = x[0], pjy = x[1], pjz = x[2];
    volatile unsigned* vsl = (volatile unsigned*)xslot;

    for (int i = 0; i < N_DEATH; ++i) {
        unsigned lv = 0xFFFFFFFFu;
        // fused: min-update with distance to j + masked local argmin
#pragma unroll
        for (int s = 0; s < PT; ++s) {
            float dx = px[s] - pjx, dy = py[s] - pjy, dz = pz[s] - pjz;
            float d2 = dx * dx + dy * dy + dz * dz;
            unsigned pk = (__float_as_uint(d2) & 0xFFFFF000u) | idxs[s];
            unsigned nm = m[s] < pk ? m[s] : pk;
            m[s] = nm;
            // sext of visited bit s -> 0 or 0xFFFFFFFF; visited cands lose
            unsigned ext = (unsigned)__builtin_amdgcn_sbfe((int)vis, s, 1);
            unsigned cand = nm | ext;
            lv = lv < cand ? lv : cand;
        }
        unsigned wmin = dpp_umin6(lv);
        unsigned smin = (unsigned)__builtin_amdgcn_readlane((int)wmin, 63);
        const unsigned tag = ((unsigned)(i >> 1) & 1u) << 11;
        const int base = (i & 1) * NW;
        // clear bit 11 (all-visited sentinel protection), then stamp tag
        if (lane == 63) vsl[base + wid] = (smin & 0xFFFFF7FFu) | tag;
        // poll all 4 slots until every tag matches this iteration
        unsigned v0, v1, v2, v3;
        for (;;) {
            v0 = vsl[base + 0]; v1 = vsl[base + 1];
            v2 = vsl[base + 2]; v3 = vsl[base + 3];
            unsigned bad = ((v0 ^ tag) | (v1 ^ tag) | (v2 ^ tag) | (v3 ^ tag)) & 0x800u;
            if (!bad) break;
        }
        unsigned w01 = v0 < v1 ? v0 : v1;
        unsigned w23 = v2 < v3 ? v2 : v3;
        unsigned win = w01 < w23 ? w01 : w23;
        j = (int)(win & 0x7FFu);
        // mark new j visited in its owner thread
        vis |= (t == (j >> 3)) ? (1u << (j & 7)) : 0u;
        float4 pj = pp[j];                       // broadcast read, conflict-free
        pjx = pj.x; pjy = pj.y; pjz = pj.z;
        if (t == 0) deaths[i] = sqrtf(__uint_as_float(win & 0xFFFFF000u));
    }

    // pad then bitonic sort DESCENDING
    if (t < SORT_N - N_DEATH) deaths[N_DEATH + t] = -BIG;
    __syncthreads();

    for (int k = 2; k <= SORT_N; k <<= 1) {
        for (int jj = k >> 1; jj > 0; jj >>= 1) {
#pragma unroll
            for (int s = 0; s < SORT_N / TPB; ++s) {
                int ii = t + s * TPB;
                int ixj = ii ^ jj;
                if (ixj > ii) {
                    float a = deaths[ii], c = deaths[ixj];
                    bool descBlock = ((ii & k) == 0);
                    bool doSwap = descBlock ? (a < c) : (a > c);
                    if (doSwap) { deaths[ii] = c; deaths[ixj] = a; }
                }
            }
            __syncthreads();
        }
    }

    for (int e = t; e < N_DEATH; e += TPB)
        topo[b * N_DEATH + e] = deaths[e];
}

// Two-stage loss (used when d_ws has room for the 512 B partials buffer)
__global__ __launch_bounds__(256)
void partial_loss(const float* __restrict__ pred,
                  const float* __restrict__ tgt,
                  const float* __restrict__ topo,
                  float2* __restrict__ part) {
    const int t = threadIdx.x;
    const int gid = blockIdx.x * 256 + t;       // 0..16383
    const float4* p4 = (const float4*)pred;
    const float4* t4 = (const float4*)tgt;
    float4 a = p4[gid], c = t4[gid];            // exactly one float4 per thread
    float dx = a.x - c.x, dy = a.y - c.y, dz = a.z - c.z, dw = a.w - c.w;
    float msum = dx * dx + dy * dy + dz * dz + dw * dw;
    float tsum = 0.f;
    const int nt = BATCH * N_DEATH;             // 65440
    for (int e = gid; e < nt; e += 64 * 256) {
        float d = topo[e] - topo[e + nt];
        tsum += d * d;
    }
    __shared__ float sm[2][4];
#pragma unroll
    for (int off = 32; off >= 1; off >>= 1) {
        msum += __shfl_xor(msum, off);
        tsum += __shfl_xor(tsum, off);
    }
    int lane = t & 63, wid = t >> 6;
    if (lane == 0) { sm[0][wid] = msum; sm[1][wid] = tsum; }
    __syncthreads();
    if (t == 0) {
        float M = 0.f, T = 0.f;
#pragma unroll
        for (int w = 0; w < 4; ++w) { M += sm[0][w]; T += sm[1][w]; }
        part[blockIdx.x] = make_float2(M, T);
    }
}

__global__ __launch_bounds__(64)
void final_loss(const float2* __restrict__ part, float* __restrict__ out) {
    const int t = threadIdx.x;
    float2 p = part[t];
    float M = p.x, T = p.y;
#pragma unroll
    for (int off = 32; off >= 1; off >>= 1) {
        M += __shfl_xor(M, off);
        T += __shfl_xor(T, off);
    }
    if (t == 0)
        out[0] = M / (float)(BATCH * LLEN) + 0.1f * (T / (float)(BATCH * N_DEATH));
}

// Fallback: single-block deterministic reduction (no extra scratch needed)
#define RTPB 1024
__global__ __launch_bounds__(RTPB)
void loss_kernel(const float* __restrict__ pred,
                 const float* __restrict__ tgt,
                 const float* __restrict__ topo,
                 float* __restrict__ out) {
    const int t = threadIdx.x;
    float msum = 0.f;
    const float4* p4 = (const float4*)pred;
    const float4* t4 = (const float4*)tgt;
    const int n4 = (BATCH * LLEN) / 4;   // 16384
    for (int e = t; e < n4; e += RTPB) {
        float4 a = p4[e], c = t4[e];
        float dx = a.x - c.x, dy = a.y - c.y, dz = a.z - c.z, dw = a.w - c.w;
        msum += dx * dx + dy * dy + dz * dz + dw * dw;
    }
    float tsum = 0.f;
    const int nt = BATCH * N_DEATH;      // 65440
    for (int e = t; e < nt; e += RTPB) {
        float d = topo[e] - topo[e + nt];
        tsum += d * d;
    }
    __shared__ float sm[2][RTPB / 64];
#pragma unroll
    for (int off = 32; off >= 1; off >>= 1) {
        msum += __shfl_xor(msum, off);
        tsum += __shfl_xor(tsum, off);
    }
    int lane = t & 63, wid = t >> 6;
    if (lane == 0) { sm[0][wid] = msum; sm[1][wid] = tsum; }
    __syncthreads();
    if (t == 0) {
        float M = 0.f, T = 0.f;
#pragma unroll
        for (int w = 0; w < RTPB / 64; ++w) { M += sm[0][w]; T += sm[1][w]; }
        out[0] = M / (float)(BATCH * LLEN) + 0.1f * (T / (float)nt);
    }
}

extern "C" void kernel_launch(void* const* d_in, const int* in_sizes, int n_in,
                              void* d_out, int out_size, void* d_ws, size_t ws_size,
                              hipStream_t stream) {
    const float* pred = (const float*)d_in[0];
    const float* tgt  = (const float*)d_in[1];
    const size_t topo_bytes = (size_t)64 * N_DEATH * 4;   // 523,520 B
    float* topo = (float*)d_ws;

    topo_kernel<<<2 * BATCH, TPB, 0, stream>>>(pred, tgt, topo);

    if (ws_size >= topo_bytes + 64 * sizeof(float2)) {
        float2* part = (float2*)((char*)d_ws + topo_bytes);
        partial_loss<<<64, 256, 0, stream>>>(pred, tgt, topo, part);
        final_loss<<<1, 64, 0, stream>>>(part, (float*)d_out);
    } else {
        loss_kernel<<<1, RTPB, 0, stream>>>(pred, tgt, topo, (float*)d_out);
    }
}

// Round 5
// 800.440 us; speedup vs baseline: 3.3866x; 1.4126x over previous
//
#include <hip/hip_runtime.h>
#include <math.h>

// Problem constants (reference: B=32, L=2048)
#define LLEN 2048
#define BATCH 32
#define N_PTS (LLEN - 2)     // 2046 embedded points
#define N_DEATH (LLEN - 3)   // 2045 MST edges / deaths
#define SORT_N 2048
#define TPB 256              // 4 waves, one per SIMD
#define PT 8                 // elements per thread
#define NW 4                 // waves per block
#define BIG 1e30f

// Wave64 unsigned-min via DPP (VALU pipe). Result valid in lane 63.
__device__ __forceinline__ unsigned dpp_umin6(unsigned v) {
    unsigned t;
    t = (unsigned)__builtin_amdgcn_update_dpp(-1, (int)v, 0x111, 0xF, 0xF, false); // row_shr:1
    v = t < v ? t : v;
    t = (unsigned)__builtin_amdgcn_update_dpp(-1, (int)v, 0x112, 0xF, 0xF, false); // row_shr:2
    v = t < v ? t : v;
    t = (unsigned)__builtin_amdgcn_update_dpp(-1, (int)v, 0x114, 0xF, 0xF, false); // row_shr:4
    v = t < v ? t : v;
    t = (unsigned)__builtin_amdgcn_update_dpp(-1, (int)v, 0x118, 0xF, 0xF, false); // row_shr:8
    v = t < v ? t : v;
    t = (unsigned)__builtin_amdgcn_update_dpp(-1, (int)v, 0x142, 0xF, 0xF, false); // row_bcast:15
    v = t < v ? t : v;
    t = (unsigned)__builtin_amdgcn_update_dpp(-1, (int)v, 0x143, 0xF, 0xF, false); // row_bcast:31
    v = t < v ? t : v;
    return v;
}

// One block per series. Prim with packed (d2|idx) u32 candidates; lock-free
// polled LDS mailbox (protocol proven in round 4, incl. the bit-11 sentinel
// clear that fixes the all-visited-wave deadlock).
// ROUND-5 DELTA (hypothesis: volatile poll reads were serialized by the
// backend into per-read s_waitcnt lgkmcnt(0), ~520 cyc/iter):
//   * mailbox uses relaxed workgroup-scope atomics -> 4 loads issue
//     back-to-back, ONE waitcnt before the tag check.
//   * lane 63 publishes wmin directly (v_readlane dropped).
//   * scan pack via (d2 & mask) | idx -> v_and_or_b32 (11 inst/elem), split
//     lv accumulator chains.
//   * deaths[] stores raw d2 (sqrt deferred to the parallel epilogue; sort
//     order is preserved since sqrt is monotone on [0, inf)).
__global__ __launch_bounds__(TPB)
void topo_kernel(const float* __restrict__ pred,
                 const float* __restrict__ tgt,
                 float* __restrict__ topo /* [64][N_DEATH] */) {
    __shared__ float4 pp[SORT_N];
    __shared__ float deaths[SORT_N];     // raw d2 during Prim
    __shared__ unsigned xslot[2 * NW];   // polled mailbox [buf][wave]

    const int b = blockIdx.x;
    const float* x = (b < BATCH) ? (pred + b * LLEN) : (tgt + (b - BATCH) * LLEN);
    const int t = threadIdx.x;
    const int lane = t & 63;
    const int wid = t >> 6;

    // mailbox init: tag bit = 1 mismatches iteration 0/1's expected tag 0
    if (t < 2 * NW) xslot[t] = 0x800u;

    float px[PT], py[PT], pz[PT];
    unsigned m[PT];      // packed running min-distance (d2_hi20 | 0 | idx)
    unsigned idxs[PT];
    unsigned vis = 0;    // bit s: vertex t*PT+s is visited (or padding)
#pragma unroll
    for (int s = 0; s < PT; ++s) {
        int idx = t * PT + s;
        idxs[s] = (unsigned)idx;
        bool valid = idx < N_PTS;
        px[s] = valid ? x[idx]     : 0.f;
        py[s] = valid ? x[idx + 1] : 0.f;
        pz[s] = valid ? x[idx + 2] : 0.f;
        pp[idx] = make_float4(px[s], py[s], pz[s], 0.f);
        m[s] = 0x7F800000u | idxs[s];           // +inf packed
        if (!valid || idx == 0) vis |= 1u << s; // pads + start vertex visited
    }
    __syncthreads();   // pp[] + mailbox init visible (only barrier before sort)

    float pjx = x[0], pjy = x[1], pjz = x[2];

    for (int i = 0; i < N_DEATH; ++i) {
        // fused: min-update with distance to j + masked local argmin.
        // Two split accumulators shorten the dependence tail.
        unsigned lv0 = 0xFFFFFFFFu, lv1 = 0xFFFFFFFFu;
#pragma unroll
        for (int s = 0; s < PT; ++s) {
            float dx = px[s] - pjx, dy = py[s] - pjy, dz = pz[s] - pjz;
            float d2 = dx * dx + dy * dy + dz * dz;
            // (d2 & 0xFFFFF000) | idx -> single v_and_or_b32
            unsigned pk = (__float_as_uint(d2) & 0xFFFFF000u) | idxs[s];
            unsigned nm = m[s] < pk ? m[s] : pk;
            m[s] = nm;
            // sext of visited bit s -> 0 or 0xFFFFFFFF; visited cands lose
            unsigned ext = (unsigned)__builtin_amdgcn_sbfe((int)vis, s, 1);
            unsigned cand = nm | ext;
            if (s & 1) lv1 = lv1 < cand ? lv1 : cand;
            else       lv0 = lv0 < cand ? lv0 : cand;
        }
        unsigned lv = lv0 < lv1 ? lv0 : lv1;
        unsigned wmin = dpp_umin6(lv);           // valid in lane 63
        const unsigned tag = ((unsigned)(i >> 1) & 1u) << 11;
        const int base = (i & 1) * NW;
        // lane 63 publishes directly: clear bit 11 (all-visited sentinel
        // protection), stamp tag. No readlane on the publish path.
        if (lane == 63) {
            unsigned clean = (wmin & 0xFFFFF7FFu) | tag;
            __hip_atomic_store(&xslot[base + wid], clean,
                               __ATOMIC_RELAXED, __HIP_MEMORY_SCOPE_WORKGROUP);
        }
        // poll: 4 relaxed loads issue back-to-back -> one waitcnt per round
        unsigned v0, v1, v2, v3;
        for (;;) {
            v0 = __hip_atomic_load(&xslot[base + 0], __ATOMIC_RELAXED, __HIP_MEMORY_SCOPE_WORKGROUP);
            v1 = __hip_atomic_load(&xslot[base + 1], __ATOMIC_RELAXED, __HIP_MEMORY_SCOPE_WORKGROUP);
            v2 = __hip_atomic_load(&xslot[base + 2], __ATOMIC_RELAXED, __HIP_MEMORY_SCOPE_WORKGROUP);
            v3 = __hip_atomic_load(&xslot[base + 3], __ATOMIC_RELAXED, __HIP_MEMORY_SCOPE_WORKGROUP);
            unsigned bad = ((v0 ^ tag) | (v1 ^ tag) | (v2 ^ tag) | (v3 ^ tag)) & 0x800u;
            if (!bad) break;
        }
        unsigned w01 = v0 < v1 ? v0 : v1;
        unsigned w23 = v2 < v3 ? v2 : v3;
        unsigned win = w01 < w23 ? w01 : w23;
        int j = (int)(win & 0x7FFu);
        // mark new j visited in its owner thread
        vis |= (t == (j >> 3)) ? (1u << (j & 7)) : 0u;
        float4 pj = pp[j];                       // broadcast read, conflict-free
        pjx = pj.x; pjy = pj.y; pjz = pj.z;
        if (t == 0) deaths[i] = __uint_as_float(win & 0xFFFFF000u); // raw d2
    }

    // pad then bitonic sort DESCENDING on d2 (sqrt is monotone -> same order)
    if (t < SORT_N - N_DEATH) deaths[N_DEATH + t] = -BIG;
    __syncthreads();

    for (int k = 2; k <= SORT_N; k <<= 1) {
        for (int jj = k >> 1; jj > 0; jj >>= 1) {
#pragma unroll
            for (int s = 0; s < SORT_N / TPB; ++s) {
                int ii = t + s * TPB;
                int ixj = ii ^ jj;
                if (ixj > ii) {
                    float a = deaths[ii], c = deaths[ixj];
                    bool descBlock = ((ii & k) == 0);
                    bool doSwap = descBlock ? (a < c) : (a > c);
                    if (doSwap) { deaths[ii] = c; deaths[ixj] = a; }
                }
            }
            __syncthreads();
        }
    }

    for (int e = t; e < N_DEATH; e += TPB)
        topo[b * N_DEATH + e] = sqrtf(deaths[e]);   // sqrt deferred to here
}

// Two-stage loss (used when d_ws has room for the 512 B partials buffer)
__global__ __launch_bounds__(256)
void partial_loss(const float* __restrict__ pred,
                  const float* __restrict__ tgt,
                  const float* __restrict__ topo,
                  float2* __restrict__ part) {
    const int t = threadIdx.x;
    const int gid = blockIdx.x * 256 + t;       // 0..16383
    const float4* p4 = (const float4*)pred;
    const float4* t4 = (const float4*)tgt;
    float4 a = p4[gid], c = t4[gid];            // exactly one float4 per thread
    float dx = a.x - c.x, dy = a.y - c.y, dz = a.z - c.z, dw = a.w - c.w;
    float msum = dx * dx + dy * dy + dz * dz + dw * dw;
    float tsum = 0.f;
    const int nt = BATCH * N_DEATH;             // 65440
    for (int e = gid; e < nt; e += 64 * 256) {
        float d = topo[e] - topo[e + nt];
        tsum += d * d;
    }
    __shared__ float sm[2][4];
#pragma unroll
    for (int off = 32; off >= 1; off >>= 1) {
        msum += __shfl_xor(msum, off);
        tsum += __shfl_xor(tsum, off);
    }
    int lane = t & 63, wid = t >> 6;
    if (lane == 0) { sm[0][wid] = msum; sm[1][wid] = tsum; }
    __syncthreads();
    if (t == 0) {
        float M = 0.f, T = 0.f;
#pragma unroll
        for (int w = 0; w < 4; ++w) { M += sm[0][w]; T += sm[1][w]; }
        part[blockIdx.x] = make_float2(M, T);
    }
}

__global__ __launch_bounds__(64)
void final_loss(const float2* __restrict__ part, float* __restrict__ out) {
    const int t = threadIdx.x;
    float2 p = part[t];
    float M = p.x, T = p.y;
#pragma unroll
    for (int off = 32; off >= 1; off >>= 1) {
        M += __shfl_xor(M, off);
        T += __shfl_xor(T, off);
    }
    if (t == 0)
        out[0] = M / (float)(BATCH * LLEN) + 0.1f * (T / (float)(BATCH * N_DEATH));
}

// Fallback: single-block deterministic reduction (no extra scratch needed)
#define RTPB 1024
__global__ __launch_bounds__(RTPB)
void loss_kernel(const float* __restrict__ pred,
                 const float* __restrict__ tgt,
                 const float* __restrict__ topo,
                 float* __restrict__ out) {
    const int t = threadIdx.x;
    float msum = 0.f;
    const float4* p4 = (const float4*)pred;
    const float4* t4 = (const float4*)tgt;
    const int n4 = (BATCH * LLEN) / 4;   // 16384
    for (int e = t; e < n4; e += RTPB) {
        float4 a = p4[e], c = t4[e];
        float dx = a.x - c.x, dy = a.y - c.y, dz = a.z - c.z, dw = a.w - c.w;
        msum += dx * dx + dy * dy + dz * dz + dw * dw;
    }
    float tsum = 0.f;
    const int nt = BATCH * N_DEATH;      // 65440
    for (int e = t; e < nt; e += RTPB) {
        float d = topo[e] - topo[e + nt];
        tsum += d * d;
    }
    __shared__ float sm[2][RTPB / 64];
#pragma unroll
    for (int off = 32; off >= 1; off >>= 1) {
        msum += __shfl_xor(msum, off);
        tsum += __shfl_xor(tsum, off);
    }
    int lane = t & 63, wid = t >> 6;
    if (lane == 0) { sm[0][wid] = msum; sm[1][wid] = tsum; }
    __syncthreads();
    if (t == 0) {
        float M = 0.f, T = 0.f;
#pragma unroll
        for (int w = 0; w < RTPB / 64; ++w) { M += sm[0][w]; T += sm[1][w]; }
        out[0] = M / (float)(BATCH * LLEN) + 0.1f * (T / (float)nt);
    }
}

extern "C" void kernel_launch(void* const* d_in, const int* in_sizes, int n_in,
                              void* d_out, int out_size, void* d_ws, size_t ws_size,
                              hipStream_t stream) {
    const float* pred = (const float*)d_in[0];
    const float* tgt  = (const float*)d_in[1];
    const size_t topo_bytes = (size_t)64 * N_DEATH * 4;   // 523,520 B
    float* topo = (float*)d_ws;

    topo_kernel<<<2 * BATCH, TPB, 0, stream>>>(pred, tgt, topo);

    if (ws_size >= topo_bytes + 64 * sizeof(float2)) {
        float2* part = (float2*)((char*)d_ws + topo_bytes);
        partial_loss<<<64, 256, 0, stream>>>(pred, tgt, topo, part);
        final_loss<<<1, 64, 0, stream>>>(part, (float*)d_out);
    } else {
        loss_kernel<<<1, RTPB, 0, stream>>>(pred, tgt, topo, (float*)d_out);
    }
}